// Round 8
// baseline (42.658 us; speedup 1.0000x reference)
//
#include <hip/hip_runtime.h>

typedef _Float16 f16;
typedef __attribute__((ext_vector_type(8))) _Float16 f16x8;
typedef __attribute__((ext_vector_type(4))) _Float16 f16x4;
typedef __attribute__((ext_vector_type(4))) float f32x4;

// Barrier that does NOT drain vmcnt: LDS ordering via lgkmcnt(0); global
// prefetches stay in flight. sched_barrier keeps MFMA from hoisting past it.
#define BARRIER()                                              \
    do {                                                       \
        asm volatile("s_waitcnt lgkmcnt(0)" ::: "memory");     \
        __builtin_amdgcn_s_barrier();                          \
        __builtin_amdgcn_sched_barrier(0);                     \
    } while (0)

namespace {
constexpr int kL   = 65536;
constexpr int kR   = 256;
constexpr int kD   = 64;
constexpr int kDV  = 64;

constexpr int kABlocks = 512;   // 128 cols each (2 chunks of 64)
constexpr int kBBlocks = 512;   // 128 cols each (2 chunks of 64)
constexpr int kRBlocks = 128;   // 128 outputs each

constexpr float kBc   = 0.7745966692414834f;      // sqrt(0.6)
// base = kAc + ln(kDnS) - ||x||^2 ; kAc=0.1, ln(0.6^16*2^10) = -1.241740526
constexpr float kBase0 = -1.1417405264f;
constexpr float kOutScale = 9.5367431640625e-7f;  // 2^-20 undoes PHI_SCALE^2
}

// ---------------------------------------------------------------------------
// Kernel A: partials[blk][dv][r] (f16) = (phi(K_cols)*2^10 @ V_cols)^T
// Double-buffered staging: stage(c+1) overlaps z/phi(c); 4 barriers total.
// ---------------------------------------------------------------------------
__global__ __launch_bounds__(512, 2)
void favor_kv(const float* __restrict__ Kg, const float* __restrict__ Vg,
              const float* __restrict__ Wg, f16* __restrict__ partials)
{
    __shared__ f16 sXt[2][64 * 64];   // K chunk [l][d], swizzled
    __shared__ f16 sVt[2][64 * 64];   // V chunk [dv][l], swizzled
    __shared__ f16 sPhi[256 * 64];    // [r][l], swizzled (single buffer)
    __shared__ float sRed[2][8 * 64]; // per-wave norm partials
    __shared__ float sRedT[2][64];    // total column norms

    const int tid  = threadIdx.x;
    const int w    = tid >> 6;
    const int lane = tid & 63;
    const int l15  = lane & 15;
    const int lhi  = lane >> 4;
    const int blk  = blockIdx.x;
    const int lblk = blk * 128;

    const int scol  = lane;
    const int dbase = w * 8;

    // ---- issue ALL global loads up front
    float ka[2][8], va[2][8];
#pragma unroll
    for (int c = 0; c < 2; ++c) {
        const int l0 = lblk + c * 64;
#pragma unroll
        for (int j = 0; j < 8; ++j) ka[c][j] = Kg[(dbase + j) * kL + l0 + scol];
#pragma unroll
        for (int j = 0; j < 8; ++j) va[c][j] = Vg[(size_t)(l0 + dbase + j) * kDV + scol];
    }

    // W fragments (B-operand: col = l15 -> r, k = 8*lhi+j -> d)
    f16x8 wfrag[2][2];
#pragma unroll
    for (int ri = 0; ri < 2; ++ri)
#pragma unroll
        for (int ks = 0; ks < 2; ++ks) {
            const float* p = Wg + (32 * w + 16 * ri + l15) * kD + 32 * ks + 8 * lhi;
            f16x8 v;
#pragma unroll
            for (int j = 0; j < 8; ++j) v[j] = (f16)p[j];
            wfrag[ri][ks] = v;
        }

    f32x4 acc[4][2];
#pragma unroll
    for (int a = 0; a < 4; ++a)
#pragma unroll
        for (int d = 0; d < 2; ++d) { f32x4 z0 = {0.f, 0.f, 0.f, 0.f}; acc[a][d] = z0; }

    const int wr = w >> 1;     // PV r-group (64 rows)
    const int wc = w & 1;      // PV dv half (32 cols)

    auto stage = [&](int c) {
        float s = 0.f;
        f16x8 hk, hv;
#pragma unroll
        for (int j = 0; j < 8; ++j) {
            const float x = ka[c][j];
            s += x * x;
            hk[j] = (f16)x;
            hv[j] = (f16)va[c][j];
        }
        sRed[c][w * 64 + scol] = s;
        *(f16x8*)&sXt[c][scol * 64 + (dbase ^ ((scol & 7) << 3))] = hk;
        *(f16x8*)&sVt[c][scol * 64 + (dbase ^ ((scol & 7) << 3))] = hv;
    };

    auto norms = [&](int c) {
        float sqv = 0.f;
#pragma unroll
        for (int g = 0; g < 8; ++g) sqv += sRed[c][g * 64 + lane];
        sRedT[c][lane] = sqv;
    };

    auto zphi = [&](int c) {
        // base per column (4 consecutive l per lane slot), reused by both ri
        f32x4 base4[4];
#pragma unroll
        for (int lf = 0; lf < 4; ++lf) {
            const f32x4 sq4 = *(const f32x4*)&sRedT[c][16 * lf + 4 * lhi];
#pragma unroll
            for (int j = 0; j < 4; ++j) base4[lf][j] = kBase0 - sq4[j];
        }
#pragma unroll
        for (int ri = 0; ri < 2; ++ri) {
            f32x4 z[4];
#pragma unroll
            for (int lf = 0; lf < 4; ++lf) { f32x4 z0 = {0.f, 0.f, 0.f, 0.f}; z[lf] = z0; }
            __builtin_amdgcn_s_setprio(1);
#pragma unroll
            for (int ks = 0; ks < 2; ++ks) {
                f16x8 bfr[4];
#pragma unroll
                for (int lf = 0; lf < 4; ++lf) {
                    const int row = 16 * lf + l15;
                    bfr[lf] = *(const f16x8*)&sXt[c][row * 64 + ((32 * ks + 8 * lhi) ^ ((row & 7) << 3))];
                }
#pragma unroll
                for (int lf = 0; lf < 4; ++lf)
                    z[lf] = __builtin_amdgcn_mfma_f32_16x16x32_f16(bfr[lf], wfrag[ri][ks], z[lf], 0, 0, 0);
            }
            __builtin_amdgcn_s_setprio(0);
            const int r = 32 * w + 16 * ri + l15;
#pragma unroll
            for (int lf = 0; lf < 4; ++lf) {
                f16x4 ph;
#pragma unroll
                for (int j = 0; j < 4; ++j)
                    ph[j] = (f16)__expf(fmaf(z[lf][j], kBc, base4[lf][j]));
                const int lbase = 16 * lf + 4 * lhi;
                *(f16x4*)&sPhi[r * 64 + (lbase ^ ((r & 7) << 3))] = ph;
            }
        }
    };

    auto pv = [&](int c) {
        __builtin_amdgcn_s_setprio(1);
#pragma unroll
        for (int ks = 0; ks < 2; ++ks) {
            f16x8 af[4], bf[2];
#pragma unroll
            for (int ai = 0; ai < 4; ++ai) {
                const int r = 64 * wr + 16 * ai + l15;
                af[ai] = *(const f16x8*)&sPhi[r * 64 + ((32 * ks + 8 * lhi) ^ ((r & 7) << 3))];
            }
#pragma unroll
            for (int di = 0; di < 2; ++di) {
                const int dv = 32 * wc + 16 * di + l15;
                bf[di] = *(const f16x8*)&sVt[c][dv * 64 + ((32 * ks + 8 * lhi) ^ ((dv & 7) << 3))];
            }
#pragma unroll
            for (int ai = 0; ai < 4; ++ai)
#pragma unroll
                for (int di = 0; di < 2; ++di)
                    acc[ai][di] = __builtin_amdgcn_mfma_f32_16x16x32_f16(af[ai], bf[di], acc[ai][di], 0, 0, 0);
        }
        __builtin_amdgcn_s_setprio(0);
    };

    stage(0);
    BARRIER();
    norms(0);
    zphi(0);     // writes sPhi
    stage(1);    // writes buf 1 (no conflict with buf-0 readers)
    BARRIER();
    norms(1);
    pv(0);       // reads sPhi + sVt[0]
    BARRIER();   // PV0 done reading sPhi before phi1 overwrites
    zphi(1);
    BARRIER();
    pv(1);

    // ---- per-block partial, stored TRANSPOSED [dv][r]
    f16* po = partials + (size_t)blk * (kR * kDV);
#pragma unroll
    for (int ai = 0; ai < 4; ++ai)
#pragma unroll
        for (int di = 0; di < 2; ++di) {
            const int dv = 32 * wc + 16 * di + l15;
            f16x4 pk;
#pragma unroll
            for (int j = 0; j < 4; ++j) pk[j] = (f16)acc[ai][di][j];
            *(f16x4*)&po[dv * kR + 64 * wr + 16 * ai + 4 * lhi] = pk;
        }
}

// ---------------------------------------------------------------------------
// Kernel R: kvT[o] = sum over 512 slices of partials[s][o]  (o = dv*256 + r)
// ---------------------------------------------------------------------------
__global__ __launch_bounds__(512)
void favor_reduce(const f16* __restrict__ partials, f16* __restrict__ kvT)
{
    __shared__ float sAcc[32][128];
    const int tid  = threadIdx.x;
    const int slot = tid & 15;
    const int g    = tid >> 4;
    const size_t obase = (size_t)blockIdx.x * 128 + slot * 8;

    float a[8] = {0.f, 0.f, 0.f, 0.f, 0.f, 0.f, 0.f, 0.f};
#pragma unroll 4
    for (int i = 0; i < 16; ++i) {
        const int s = g * 16 + i;
        const f16x8 v = *(const f16x8*)&partials[(size_t)s * (kR * kDV) + obase];
#pragma unroll
        for (int j = 0; j < 8; ++j) a[j] += (float)v[j];
    }
#pragma unroll
    for (int j = 0; j < 8; ++j) sAcc[g][slot * 8 + j] = a[j];
    __syncthreads();

    if (tid < 128) {
        float tot = 0.f;
#pragma unroll
        for (int gg = 0; gg < 32; ++gg) tot += sAcc[gg][tid];
        kvT[(size_t)blockIdx.x * 128 + tid] = (f16)tot;
    }
}

// ---------------------------------------------------------------------------
// Kernel B: out = (phi(Q)*2^10)^T @ kv, scaled 2^-20.
// kv fragments register-resident (prefetched, reused across both chunks);
// double-buffered Q staging; 4 barriers.
// ---------------------------------------------------------------------------
__global__ __launch_bounds__(512, 2)
void favor_out(const float* __restrict__ Qg, const float* __restrict__ Wg,
               const f16* __restrict__ kvT, float* __restrict__ outg)
{
    __shared__ f16 sXt[2][64 * 64];   // Q chunk [l][d], swizzled
    __shared__ f16 sPhiT[64 * 256];   // [l][r], swizzled (single buffer)
    __shared__ float sRed[2][8 * 64];

    const int tid  = threadIdx.x;
    const int w    = tid >> 6;
    const int lane = tid & 63;
    const int l15  = lane & 15;
    const int lhi  = lane >> 4;
    const int blk  = blockIdx.x;
    const int lblk = blk * 128;

    const int scol  = lane;
    const int dbase = w * 8;
    const int lfo = w >> 1;
    const int dvh = w & 1;

    // ---- prologue loads: Q both chunks, kv fragments, W fragments
    float qa[2][8];
#pragma unroll
    for (int c = 0; c < 2; ++c)
#pragma unroll
        for (int j = 0; j < 8; ++j)
            qa[c][j] = Qg[(dbase + j) * kL + lblk + c * 64 + scol];

    f16x8 kvf[2][8];  // B-operand frags: rows dv, k = r
#pragma unroll
    for (int di = 0; di < 2; ++di) {
        const int dv = 32 * dvh + 16 * di + l15;
#pragma unroll
        for (int ks = 0; ks < 8; ++ks)
            kvf[di][ks] = *(const f16x8*)&kvT[dv * kR + 32 * ks + 8 * lhi];
    }

    f16x8 wfrag[2][2];
#pragma unroll
    for (int ri = 0; ri < 2; ++ri)
#pragma unroll
        for (int ks = 0; ks < 2; ++ks) {
            const float* p = Wg + (32 * w + 16 * ri + l15) * kD + 32 * ks + 8 * lhi;
            f16x8 v;
#pragma unroll
            for (int j = 0; j < 8; ++j) v[j] = (f16)p[j];
            wfrag[ri][ks] = v;
        }

    auto stageQ = [&](int c) {
        float s = 0.f;
        f16x8 hq;
#pragma unroll
        for (int j = 0; j < 8; ++j) {
            const float x = qa[c][j];
            s += x * x;
            hq[j] = (f16)x;
        }
        sRed[c][w * 64 + scol] = s;
        *(f16x8*)&sXt[c][scol * 64 + (dbase ^ ((scol & 7) << 3))] = hq;
    };

    auto zphiQ = [&](int c) {
        float sqv = 0.f;
#pragma unroll
        for (int g = 0; g < 8; ++g) sqv += sRed[c][g * 64 + lane];
        float tbase[4];
#pragma unroll
        for (int lf = 0; lf < 4; ++lf)
            tbase[lf] = kBase0 - __shfl(sqv, lf * 16 + l15, 64);

#pragma unroll
        for (int ri = 0; ri < 2; ++ri) {
            f32x4 z[4];
#pragma unroll
            for (int lf = 0; lf < 4; ++lf) { f32x4 z0 = {0.f, 0.f, 0.f, 0.f}; z[lf] = z0; }
            __builtin_amdgcn_s_setprio(1);
#pragma unroll
            for (int ks = 0; ks < 2; ++ks) {
                f16x8 bfr[4];
#pragma unroll
                for (int lf = 0; lf < 4; ++lf) {
                    const int row = 16 * lf + l15;
                    bfr[lf] = *(const f16x8*)&sXt[c][row * 64 + ((32 * ks + 8 * lhi) ^ ((row & 7) << 3))];
                }
#pragma unroll
                for (int lf = 0; lf < 4; ++lf)
                    z[lf] = __builtin_amdgcn_mfma_f32_16x16x32_f16(wfrag[ri][ks], bfr[lf], z[lf], 0, 0, 0);
            }
            __builtin_amdgcn_s_setprio(0);
            const int r0 = 32 * w + 16 * ri + 4 * lhi;
#pragma unroll
            for (int lf = 0; lf < 4; ++lf) {
                const int lc = 16 * lf + l15;
                f16x4 ph;
#pragma unroll
                for (int j = 0; j < 4; ++j)
                    ph[j] = (f16)__expf(fmaf(z[lf][j], kBc, tbase[lf]));
                *(f16x4*)&sPhiT[lc * 256 + (r0 ^ ((lc & 7) << 3))] = ph;
            }
        }
    };

    auto pvOut = [&](int c) {
        f32x4 o2[2];
        { f32x4 z0 = {0.f, 0.f, 0.f, 0.f}; o2[0] = z0; o2[1] = z0; }
        const int lrow = 16 * lfo + l15;
        __builtin_amdgcn_s_setprio(1);
#pragma unroll
        for (int ks = 0; ks < 8; ++ks) {
            const f16x8 af = *(const f16x8*)&sPhiT[lrow * 256 + ((32 * ks + 8 * lhi) ^ ((lrow & 7) << 3))];
#pragma unroll
            for (int di = 0; di < 2; ++di)
                o2[di] = __builtin_amdgcn_mfma_f32_16x16x32_f16(af, kvf[di][ks], o2[di], 0, 0, 0);
        }
        __builtin_amdgcn_s_setprio(0);
        const int l0 = lblk + c * 64;
#pragma unroll
        for (int di = 0; di < 2; ++di)
#pragma unroll
            for (int j = 0; j < 4; ++j) {
                const int ll = 16 * lfo + 4 * lhi + j;
                const int dv = 32 * dvh + 16 * di + l15;
                outg[(size_t)(l0 + ll) * kDV + dv] = o2[di][j] * kOutScale;
            }
    };

    stageQ(0);
    BARRIER();
    zphiQ(0);    // writes sPhiT
    stageQ(1);
    BARRIER();
    pvOut(0);    // reads sPhiT + reg kv
    BARRIER();   // PV0 done before phi1 overwrites sPhiT
    zphiQ(1);
    BARRIER();
    pvOut(1);
}

extern "C" void kernel_launch(void* const* d_in, const int* in_sizes, int n_in,
                              void* d_out, int out_size, void* d_ws, size_t ws_size,
                              hipStream_t stream)
{
    const float* Q = (const float*)d_in[0];
    const float* K = (const float*)d_in[1];
    const float* V = (const float*)d_in[2];
    const float* W = (const float*)d_in[3];
    float* out = (float*)d_out;

    f16* partials = (f16*)d_ws;  // 512 * 16384 f16 = 16 MiB
    f16* kvT = (f16*)((char*)d_ws + (size_t)kABlocks * kR * kDV * sizeof(f16));

    favor_kv<<<kABlocks, 512, 0, stream>>>(K, V, W, partials);
    favor_reduce<<<kRBlocks, 512, 0, stream>>>(partials, kvT);
    favor_out<<<kBBlocks, 512, 0, stream>>>(Q, W, kvT, out);

    (void)in_sizes; (void)n_in; (void)out_size; (void)ws_size;
}